// Round 1
// baseline (79.459 us; speedup 1.0000x reference)
//
#include <hip/hip_runtime.h>
#include <math.h>

#define NTX_EPS 1e-8f

// One block per (level, batch). 256 threads.
// Compute G[n][m] = sum_d ts[b,n,d] * M[b,m,d], where M = [ts;rs] (32 rows).
//   m in [0,16): t-t dots (tt);  m in [16,32): t-r dots (tr).
// Tiling: 8x8 register tiles; tile grid 2(ti) x 4(tj); 32 d-slices.
//   thread t: tile = t&7 (ti=tile>>2, tj=tile&3), slice s = t>>3.
// LDS chunk: 128 floats per row, row-major [32][132] (pad 4 floats).
__global__ __launch_bounds__(256)
void ntxent_kernel(const float* __restrict__ ts0, const float* __restrict__ rs0,
                   const float* __restrict__ ts1, const float* __restrict__ rs1,
                   const float* __restrict__ ts2, const float* __restrict__ rs2,
                   float* __restrict__ out)
{
    __shared__ float M[32][132];
    __shared__ float Gp[4][16][36];   // per-wave partial Gram
    __shared__ float rn2[16];         // ||rs row||^2
    __shared__ float tnormS[16], rnormS[16];

    const int bid = blockIdx.x;
    const int lvl = bid % 3;
    const int b   = bid / 3;

    const float* tp; const float* rp; int D;
    if (lvl == 0)      { tp = ts0; rp = rs0; D = 4096; }
    else if (lvl == 1) { tp = ts1; rp = rs1; D = 2048; }
    else               { tp = ts2; rp = rs2; D = 1024; }

    const int t    = threadIdx.x;
    // loader mapping: half (ts/rs), row 0..15, base col4 0..7 (+8*it)
    const int half = t >> 7;
    const int lrow = (t >> 3) & 15;
    const int lc4  = t & 7;
    const float* gsrc = (half ? rp : tp) + (size_t)b * 16 * D + (size_t)lrow * D;

    // compute mapping
    const int tile = t & 7;
    const int s    = t >> 3;       // 0..31: handles d in [4s, 4s+3] of each chunk
    const int ti   = tile >> 2;    // 0..1  -> output rows ti*8..ti*8+7
    const int tj   = tile & 3;     // 0..3  -> output cols tj*8..tj*8+7 (M rows)

    float acc[8][8];
#pragma unroll
    for (int i = 0; i < 8; ++i)
#pragma unroll
        for (int j = 0; j < 8; ++j) acc[i][j] = 0.f;

    float rsq = 0.f;               // partial sum-of-squares of rs rows (half==1)

    const int nchunk = D >> 7;     // chunks of 128 floats

    // prefetch chunk 0 into registers
    float4 stg[4];
#pragma unroll
    for (int it = 0; it < 4; ++it)
        stg[it] = *(const float4*)(gsrc + (lc4 + 8*it) * 4);

    const float* Arow = &M[ti*8][0] + 4*s;
    const float* Brow = &M[tj*8][0] + 4*s;

    for (int c = 0; c < nchunk; ++c) {
        __syncthreads();           // previous compute done before overwrite
#pragma unroll
        for (int it = 0; it < 4; ++it)
            *(float4*)&M[half*16 + lrow][(lc4 + 8*it)*4] = stg[it];
        if (half) {
#pragma unroll
            for (int it = 0; it < 4; ++it)
                rsq += stg[it].x*stg[it].x + stg[it].y*stg[it].y
                     + stg[it].z*stg[it].z + stg[it].w*stg[it].w;
        }
        __syncthreads();
        // issue next chunk's global loads early (latency hides under compute)
        if (c + 1 < nchunk) {
#pragma unroll
            for (int it = 0; it < 4; ++it)
                stg[it] = *(const float4*)(gsrc + (size_t)(c+1)*128 + (lc4 + 8*it)*4);
        }
        // compute: 8x8 tile over 4 d's
        float av[8][4], bv[8][4];
#pragma unroll
        for (int r = 0; r < 8; ++r)
            *(float4*)av[r] = *(const float4*)(Arow + r*132);
#pragma unroll
        for (int r = 0; r < 8; ++r)
            *(float4*)bv[r] = *(const float4*)(Brow + r*132);
#pragma unroll
        for (int dd = 0; dd < 4; ++dd)
#pragma unroll
            for (int i = 0; i < 8; ++i)
#pragma unroll
                for (int j = 0; j < 8; ++j)
                    acc[i][j] = fmaf(av[i][dd], bv[j][dd], acc[i][j]);
    }

    // reduce acc over the 8 slices within each wave (lane bits 3..5)
#pragma unroll
    for (int i = 0; i < 8; ++i)
#pragma unroll
        for (int j = 0; j < 8; ++j) {
            float v = acc[i][j];
            v += __shfl_xor(v, 8,  64);
            v += __shfl_xor(v, 16, 64);
            v += __shfl_xor(v, 32, 64);
            acc[i][j] = v;
        }

    // rs row norms: reduce over lane bits 0..2 (8 loader threads per row)
    rsq += __shfl_xor(rsq, 1, 64);
    rsq += __shfl_xor(rsq, 2, 64);
    rsq += __shfl_xor(rsq, 4, 64);
    if (half == 1 && (t & 7) == 0) rn2[lrow] = rsq;

    // one lane-set per wave writes its tile's wave-partial Gram
    const int w = t >> 6;
    const int l = t & 63;
    if ((l >> 3) == 0) {
#pragma unroll
        for (int i = 0; i < 8; ++i)
#pragma unroll
            for (int j = 0; j < 8; ++j)
                Gp[w][ti*8 + i][tj*8 + j] = acc[i][j];
    }
    __syncthreads();

    // sum the 4 wave partials into Gp[0]
    for (int e = t; e < 512; e += 256) {
        int n = e >> 5, m = e & 31;
        Gp[0][n][m] = Gp[0][n][m] + Gp[1][n][m] + Gp[2][n][m] + Gp[3][n][m];
    }
    __syncthreads();

    if (t < 16) {
        tnormS[t] = fmaxf(sqrtf(Gp[0][t][t]), NTX_EPS);
        rnormS[t] = fmaxf(sqrtf(rn2[t]), NTX_EPS);
    }
    __syncthreads();

    float loss = 0.f;
    if (t < 16) {
        const int n = t;
        const float itn = 2.0f / tnormS[n];        // includes 1/temperature = *2
        float lg[32];
#pragma unroll
        for (int m = 0; m < 16; ++m)
            lg[m] = Gp[0][n][16 + m] * itn / rnormS[m];   // s_tr row
#pragma unroll
        for (int k = 0; k < 16; ++k)
            lg[16 + k] = Gp[0][n][k] * itn / tnormS[k];   // s_tt row
        const float pos = Gp[0][n][16 + n] * itn / rnormS[n];
        float mx = -3.4e38f;
#pragma unroll
        for (int m = 0; m < 32; ++m)
            mx = (m == 16 + n) ? mx : fmaxf(mx, lg[m]);   // exclude tt diag
        float sm = 0.f;
#pragma unroll
        for (int m = 0; m < 32; ++m)
            sm += (m == 16 + n) ? 0.f : expf(lg[m] - mx);
        loss = logf(sm) + mx - pos;
    }
    // reduce 16 row losses (lanes 0..15 of wave 0)
    loss += __shfl_xor(loss, 1, 64);
    loss += __shfl_xor(loss, 2, 64);
    loss += __shfl_xor(loss, 4, 64);
    loss += __shfl_xor(loss, 8, 64);
    if (t == 0) atomicAdd(out, loss * (1.0f / 512.0f));
}

extern "C" void kernel_launch(void* const* d_in, const int* in_sizes, int n_in,
                              void* d_out, int out_size, void* d_ws, size_t ws_size,
                              hipStream_t stream) {
    const float* ts0 = (const float*)d_in[0];
    const float* rs0 = (const float*)d_in[1];
    const float* ts1 = (const float*)d_in[2];
    const float* rs1 = (const float*)d_in[3];
    const float* ts2 = (const float*)d_in[4];
    const float* rs2 = (const float*)d_in[5];
    float* out = (float*)d_out;

    hipMemsetAsync(out, 0, sizeof(float), stream);

    const int B = in_sizes[0] / (16 * 4096);   // 256
    dim3 grid(3 * B), block(256);
    hipLaunchKernelGGL(ntxent_kernel, grid, block, 0, stream,
                       ts0, rs0, ts1, rs1, ts2, rs2, out);
}